// Round 8
// baseline (601.097 us; speedup 1.0000x reference)
//
#include <hip/hip_runtime.h>
#include <cmath>

constexpr int NN  = 50000;          // nodes
constexpr int EE  = 800000;         // raw edges
constexpr int E2C = EE + NN;        // edges incl. self loops = 850000
constexpr int DIM = 128;            // input dim to every layer's GEMM

// bucketed counting sort params
constexpr int NBUCK = 256;          // dst buckets
constexpr int BW    = 196;          // bucket width: 196*256 = 50176 >= NN
constexpr int EPT   = 16;           // edges per thread (hist / bin)
constexpr int CH    = 256 * EPT;    // 4096 edges per block
constexpr int NB_B  = (E2C + CH - 1) / CH;  // 208 blocks
constexpr int DMAX  = 256;          // degree-histogram buckets

// bf16 helpers: h is stored bf16 (gather payload); all math in fp32.
__device__ inline unsigned bf16rne(float f) {
    unsigned u = __builtin_bit_cast(unsigned, f);
    return (u + 0x7fffu + ((u >> 16) & 1u)) >> 16;     // round-nearest-even
}
__device__ inline float bflo(unsigned u) { return __builtin_bit_cast(float, u << 16); }
__device__ inline float bfhi(unsigned u) { return __builtin_bit_cast(float, u & 0xffff0000u); }

// ---------------------------------------------------------------------------
// LDS-tiled GEMM  in[N,128] @ W[128,COLS]  + fused attention coefficients.
// 256 threads; 4 x CPT register tile per thread. h output stored as bf16.
// ---------------------------------------------------------------------------
template<int COLS, int NH, int CPT>
__global__ __launch_bounds__(256) void gemm_tiled(
    const float* __restrict__ in, const float* __restrict__ W,
    const float* __restrict__ a_s, const float* __restrict__ a_d,
    unsigned short* __restrict__ hout, float* __restrict__ asrc, float* __restrict__ adst)
{
    constexpr int CG = COLS / CPT;      // col groups (16 or 8)
    constexpr int NG = 256 / CG;        // node groups (16 or 32)
    constexpr int TILE_N = NG * 4;      // 64 or 128 nodes per block
    constexpr int KT = 32;              // k tile
    constexpr int XSTR = TILE_N + 4;    // padded stride, 16B-aligned
    constexpr int NTILES = DIM / KT;    // 4
    constexpr int RL = 32 / CPT;        // lanes per head-row (4 or 8)

    __shared__ float xs[KT * XSTR];
    __shared__ float Ws[KT * COLS];

    const int tid = threadIdx.x;
    const int cc  = (tid % CG) * CPT;   // cols cc..cc+CPT-1
    const int n4  = (tid / CG) * 4;     // nodes n0+n4..n0+n4+3
    const int n0  = blockIdx.x * TILE_N;

    float acc[4][CPT] = {};

    for (int kt = 0; kt < NTILES; ++kt) {
        const int k0 = kt * KT;
        // ---- stage x (transposed) ----
        #pragma unroll
        for (int r = 0; r < TILE_N * KT / 1024; ++r) {
            int fl = tid + 256 * r;
            int nn = fl / (KT / 4);
            int kq = fl % (KT / 4);
            int row = n0 + nn; if (row >= NN) row = NN - 1;
            float4 v = *(const float4*)&in[(long long)row * DIM + k0 + kq * 4];
            xs[(kq * 4 + 0) * XSTR + nn] = v.x;
            xs[(kq * 4 + 1) * XSTR + nn] = v.y;
            xs[(kq * 4 + 2) * XSTR + nn] = v.z;
            xs[(kq * 4 + 3) * XSTR + nn] = v.w;
        }
        // ---- stage W ----
        #pragma unroll
        for (int r = 0; r < KT * COLS / 1024; ++r) {
            int fl = tid + 256 * r;
            int kk = fl / (COLS / 4);
            int cq = fl % (COLS / 4);
            *(float4*)&Ws[kk * COLS + cq * 4] =
                *(const float4*)&W[(long long)(k0 + kk) * COLS + cq * 4];
        }
        __syncthreads();
        // ---- compute ----
        #pragma unroll 8
        for (int k = 0; k < KT; ++k) {
            float4 xv4 = *(const float4*)&xs[k * XSTR + n4];
            float xv[4] = {xv4.x, xv4.y, xv4.z, xv4.w};
            float wv[CPT];
            #pragma unroll
            for (int q = 0; q < CPT / 4; ++q) {
                float4 w4 = *(const float4*)&Ws[k * COLS + cc + 4 * q];
                wv[4 * q + 0] = w4.x; wv[4 * q + 1] = w4.y;
                wv[4 * q + 2] = w4.z; wv[4 * q + 3] = w4.w;
            }
            #pragma unroll
            for (int i = 0; i < 4; ++i)
                #pragma unroll
                for (int j = 0; j < CPT; ++j)
                    acc[i][j] = fmaf(xv[i], wv[j], acc[i][j]);
        }
        __syncthreads();
    }

    // ---- epilogue: bf16 store + fused alpha reduction ----
    float asv[CPT], adv[CPT];
    #pragma unroll
    for (int j = 0; j < CPT; ++j) { asv[j] = a_s[cc + j]; adv[j] = a_d[cc + j]; }
    const int head = cc / 32;

    #pragma unroll
    for (int i = 0; i < 4; ++i) {
        const int node = n0 + n4 + i;
        const bool ok = node < NN;
        unsigned up[CPT / 2];
        #pragma unroll
        for (int j = 0; j < CPT / 2; ++j)
            up[j] = bf16rne(acc[i][2 * j]) | (bf16rne(acc[i][2 * j + 1]) << 16);
        if (ok) {
            if constexpr (CPT == 8) {
                uint4 t4; t4.x = up[0]; t4.y = up[1]; t4.z = up[2]; t4.w = up[3];
                *(uint4*)&hout[(long long)node * COLS + cc] = t4;
            } else {
                uint2 t2; t2.x = up[0]; t2.y = up[1];
                *(uint2*)&hout[(long long)node * COLS + cc] = t2;
            }
        }
        float ps = 0.f, pd = 0.f;
        #pragma unroll
        for (int j = 0; j < CPT; ++j) {
            ps = fmaf(acc[i][j], asv[j], ps);
            pd = fmaf(acc[i][j], adv[j], pd);
        }
        #pragma unroll
        for (int off = RL / 2; off > 0; off >>= 1) {
            ps += __shfl_down(ps, off, RL);
            pd += __shfl_down(pd, off, RL);
        }
        if (ok && (tid & (RL - 1)) == 0) {
            asrc[node * NH + head] = ps;
            adst[node * NH + head] = pd;
        }
    }
}

// ---------------------------------------------------------------------------
// CSR build: bucket hist -> 1-block scan -> bucket_bin -> bucket_sort
// (also emits a global degree histogram) -> degree scan -> degree perm.
// ---------------------------------------------------------------------------
__global__ __launch_bounds__(256) void bucket_hist(
    const int* __restrict__ ei, int* __restrict__ bhist)
{
    __shared__ int cnt[NBUCK];
    const int tid = threadIdx.x;
    const long long e0 = (long long)blockIdx.x * CH;
    cnt[tid] = 0;
    __syncthreads();
    #pragma unroll
    for (int j = 0; j < EPT; ++j) {
        long long e = e0 + tid + j * 256;
        if (e < E2C) {
            int dd = (e < EE) ? ei[EE + e] : (int)(e - EE);
            atomicAdd(&cnt[dd / BW], 1);
        }
    }
    __syncthreads();
    if (cnt[tid]) atomicAdd(&bhist[tid], cnt[tid]);
}

__global__ void scan_buckets(const int* __restrict__ bhist,
                             int* __restrict__ bbase, int* __restrict__ bcursor,
                             int* __restrict__ rowptr)
{
    __shared__ int tmp[NBUCK];
    const int tid = threadIdx.x;         // <<<1, 256>>>
    int v = bhist[tid];
    tmp[tid] = v;
    __syncthreads();
    for (int off = 1; off < NBUCK; off <<= 1) {
        int t = (tid >= off) ? tmp[tid - off] : 0;
        __syncthreads();
        tmp[tid] += t;
        __syncthreads();
    }
    int excl = tmp[tid] - v;
    bbase[tid]   = excl;
    bcursor[tid] = excl;
    if (tid == NBUCK - 1) bbase[NBUCK] = tmp[tid];   // == E2C
    if (tid == 0) rowptr[NN] = E2C;
}

// bin edges into bucket-grouped pairs with LDS staging (dense global writes)
__global__ __launch_bounds__(256) void bucket_bin(
    const int* __restrict__ ei, int* __restrict__ bcursor, uint2* __restrict__ pairs)
{
    __shared__ int cnt[NBUCK];
    __shared__ int scanex[NBUCK];
    __shared__ int base[NBUCK];
    __shared__ int cur[NBUCK];
    __shared__ uint2 stage[CH];

    const int tid = threadIdx.x;
    const long long e0 = (long long)blockIdx.x * CH;
    cnt[tid] = 0;
    __syncthreads();

    int s[EPT], d[EPT], bk[EPT];
    #pragma unroll
    for (int j = 0; j < EPT; ++j) {
        long long e = e0 + tid + j * 256;
        bool valid = e < E2C;
        int ss = 0, dd = 0;
        if (valid) {
            if (e < EE) { ss = ei[e]; dd = ei[EE + e]; }
            else        { ss = dd = (int)(e - EE); }
        }
        s[j] = ss; d[j] = dd;
        bk[j] = valid ? dd / BW : -1;
        if (valid) atomicAdd(&cnt[bk[j]], 1);
    }
    __syncthreads();

    const int myc = cnt[tid];
    scanex[tid] = myc;
    __syncthreads();
    for (int off = 1; off < NBUCK; off <<= 1) {
        int t = (tid >= off) ? scanex[tid - off] : 0;
        __syncthreads();
        scanex[tid] += t;
        __syncthreads();
    }
    int excl = scanex[tid] - myc;
    __syncthreads();
    scanex[tid] = excl;
    cur[tid]    = excl;
    base[tid]   = atomicAdd(&bcursor[tid], myc);   // reserve global chunk
    __syncthreads();

    #pragma unroll
    for (int j = 0; j < EPT; ++j) {
        if (bk[j] >= 0) {
            int p = atomicAdd(&cur[bk[j]], 1);
            stage[p] = make_uint2((unsigned)s[j], (unsigned)d[j]);
        }
    }
    __syncthreads();

    const int total = (e0 + CH <= E2C) ? CH : (int)(E2C - e0);
    for (int j = tid; j < total; j += 256) {
        uint2 p = stage[j];
        int b = (int)p.y / BW;
        pairs[base[b] + (j - scanex[b])] = p;
    }
}

// one block per bucket: local hist -> local scan -> rowptr + in-window scatter
// + global degree histogram (for degree-sorted node order).
__global__ __launch_bounds__(256) void bucket_sort(
    const int* __restrict__ bbase, const uint2* __restrict__ pairs,
    int* __restrict__ rowptr, int* __restrict__ sorted_src,
    int* __restrict__ dhist)
{
    __shared__ int deg[NBUCK];     // per-node degree (BW<=256)
    __shared__ int cur[NBUCK];
    const int b  = blockIdx.x;
    const int n0 = b * BW;
    const int n1 = (n0 + BW < NN) ? n0 + BW : NN;
    const int tid = threadIdx.x;
    const int beg = bbase[b], end = bbase[b + 1];

    deg[tid] = 0;
    __syncthreads();
    for (int i = beg + tid; i < end; i += 256)
        atomicAdd(&deg[(int)pairs[i].y - n0], 1);
    __syncthreads();

    // degree histogram (global)
    if (n0 + tid < n1) {
        int dg = deg[tid]; if (dg > DMAX - 1) dg = DMAX - 1;
        atomicAdd(&dhist[dg], 1);
    }

    // Hillis-Steele inclusive scan over 256 entries
    int v = deg[tid];
    cur[tid] = v;
    __syncthreads();
    for (int off = 1; off < 256; off <<= 1) {
        int t = (tid >= off) ? cur[tid - off] : 0;
        __syncthreads();
        cur[tid] += t;
        __syncthreads();
    }
    int excl = cur[tid] - v;
    __syncthreads();
    cur[tid] = beg + excl;
    if (n0 + tid < n1) rowptr[n0 + tid] = beg + excl;
    __syncthreads();

    for (int i = beg + tid; i < end; i += 256) {
        uint2 p = pairs[i];
        int pos = atomicAdd(&cur[(int)p.y - n0], 1);
        sorted_src[pos] = (int)p.x;
    }
}

__global__ void dscan(const int* __restrict__ dhist, int* __restrict__ dcursor)
{
    __shared__ int tmp[DMAX];
    const int tid = threadIdx.x;         // <<<1, 256>>>
    int v = dhist[tid];
    tmp[tid] = v;
    __syncthreads();
    for (int off = 1; off < DMAX; off <<= 1) {
        int t = (tid >= off) ? tmp[tid - off] : 0;
        __syncthreads();
        tmp[tid] += t;
        __syncthreads();
    }
    dcursor[tid] = tmp[tid] - v;
}

__global__ void dperm(const int* __restrict__ rowptr, int* __restrict__ dcursor,
                      int* __restrict__ perm)
{
    int n = blockIdx.x * 256 + threadIdx.x;
    if (n >= NN) return;
    int dg = rowptr[n + 1] - rowptr[n];
    if (dg > DMAX - 1) dg = DMAX - 1;
    int pos = atomicAdd(&dcursor[dg], 1);
    perm[pos] = n;
}

// ---------------------------------------------------------------------------
// Degree-ordered CSR gather aggregation over bf16 h: 8 channels/lane
// (uint4 = 16B), 4-edge batching, COLS/8 lanes per node. Nodes processed in
// degree-sorted order (perm) so co-wave nodes have ~equal trip counts.
// ---------------------------------------------------------------------------
template<int COLS, int NH, bool DO_ELU>
__global__ __launch_bounds__(256) void aggr_csr(
    const int* __restrict__ rowptr, const int* __restrict__ sorted_src,
    const int* __restrict__ perm,
    const unsigned short* __restrict__ hin,
    const float* __restrict__ asrc, const float* __restrict__ adst,
    const float* __restrict__ bias, float* __restrict__ out)
{
    constexpr int TPN = COLS / 8;             // lanes per node: 16 or 4
    constexpr int USTR = COLS / 2;            // uints per h row
    int t = blockIdx.x * 256 + threadIdx.x;
    int g = t / TPN;
    int lc = t % TPN;                         // owns channels 8*lc .. 8*lc+7
    if (g >= NN) return;
    const int d = perm[g];
    const int cc = lc * 8;
    const int head = cc / 32;                 // 0..NH-1
    const float ad = adst[d * NH + head];
    const int beg = rowptr[d], end = rowptr[d + 1];
    const uint* hp = (const uint*)hin;

    float num[8] = {};
    float den = 0.f;

    auto accum = [&](float w, uint4 H) {
        den += w;
        num[0] = fmaf(w, bflo(H.x), num[0]); num[1] = fmaf(w, bfhi(H.x), num[1]);
        num[2] = fmaf(w, bflo(H.y), num[2]); num[3] = fmaf(w, bfhi(H.y), num[3]);
        num[4] = fmaf(w, bflo(H.z), num[4]); num[5] = fmaf(w, bfhi(H.z), num[5]);
        num[6] = fmaf(w, bflo(H.w), num[6]); num[7] = fmaf(w, bfhi(H.w), num[7]);
    };

    int i = beg;
    for (; i + 4 <= end; i += 4) {
        int s0 = sorted_src[i];
        int s1 = sorted_src[i + 1];
        int s2 = sorted_src[i + 2];
        int s3 = sorted_src[i + 3];
        float a0 = asrc[s0 * NH + head];
        float a1 = asrc[s1 * NH + head];
        float a2 = asrc[s2 * NH + head];
        float a3 = asrc[s3 * NH + head];
        uint4 H0 = *(const uint4*)&hp[(long long)s0 * USTR + cc / 2];
        uint4 H1 = *(const uint4*)&hp[(long long)s1 * USTR + cc / 2];
        uint4 H2 = *(const uint4*)&hp[(long long)s2 * USTR + cc / 2];
        uint4 H3 = *(const uint4*)&hp[(long long)s3 * USTR + cc / 2];
        float l0 = a0 + ad; l0 = l0 > 0.f ? l0 : 0.2f * l0;
        float l1 = a1 + ad; l1 = l1 > 0.f ? l1 : 0.2f * l1;
        float l2 = a2 + ad; l2 = l2 > 0.f ? l2 : 0.2f * l2;
        float l3 = a3 + ad; l3 = l3 > 0.f ? l3 : 0.2f * l3;
        accum(__builtin_expf(l0), H0);
        accum(__builtin_expf(l1), H1);
        accum(__builtin_expf(l2), H2);
        accum(__builtin_expf(l3), H3);
    }
    for (; i < end; ++i) {
        int s = sorted_src[i];
        float a = asrc[s * NH + head];
        uint4 H = *(const uint4*)&hp[(long long)s * USTR + cc / 2];
        float l = a + ad; l = l > 0.f ? l : 0.2f * l;
        accum(__builtin_expf(l), H);
    }

    float inv = 1.f / (den + 1e-16f);
    float v[8];
    #pragma unroll
    for (int j = 0; j < 8; ++j) {
        v[j] = num[j] * inv + bias[cc + j];
        if (DO_ELU) v[j] = v[j] > 0.f ? v[j] : expm1f(v[j]);
    }
    float4 o0 = {v[0], v[1], v[2], v[3]};
    float4 o1 = {v[4], v[5], v[6], v[7]};
    *(float4*)&out[(long long)d * COLS + cc]     = o0;
    *(float4*)&out[(long long)d * COLS + cc + 4] = o1;
}

// ---------------------------------------------------------------------------
extern "C" void kernel_launch(void* const* d_in, const int* in_sizes, int n_in,
                              void* d_out, int out_size, void* d_ws, size_t ws_size,
                              hipStream_t stream)
{
    const float* x   = (const float*)d_in[0];
    const int*   ei  = (const int*)  d_in[1];
    const float* W1  = (const float*)d_in[2];
    const float* as1 = (const float*)d_in[3];
    const float* ad1 = (const float*)d_in[4];
    const float* b1  = (const float*)d_in[5];
    const float* W2  = (const float*)d_in[6];
    const float* as2 = (const float*)d_in[7];
    const float* ad2 = (const float*)d_in[8];
    const float* b2  = (const float*)d_in[9];
    const float* W3  = (const float*)d_in[10];
    const float* as3 = (const float*)d_in[11];
    const float* ad3 = (const float*)d_in[12];
    const float* b3  = (const float*)d_in[13];
    float* out = (float*)d_out;

    // workspace layout
    unsigned short* H = (unsigned short*)d_ws;            // N*128 bf16 (12.8 MB)
    float* O    = (float*)(H + (size_t)NN * 128);         // N*128 f
    float* ASRC = O + (size_t)NN * 128;                   // N*4 f
    float* ADST = ASRC + (size_t)NN * 4;                  // N*4 f
    int* rowptr = (int*)(ADST + (size_t)NN * 4);          // NN+1
    int* sorted = rowptr + (NN + 1);                      // E2C
    int* perm   = sorted + E2C;                           // NN
    int* bhist  = perm + NN;                              // NBUCK
    int* bbase  = bhist + NBUCK;                          // NBUCK+1
    int* bcursor= bbase + NBUCK + 1;                      // NBUCK
    int* dhist  = bcursor + NBUCK;                        // DMAX
    int* dcursor= dhist + DMAX;                           // DMAX
    // align pairs to 16B
    size_t off = ((size_t)(dcursor + DMAX) - (size_t)d_ws + 15) & ~(size_t)15;
    uint2* pairs = (uint2*)((char*)d_ws + off);           // E2C uint2 (6.8 MB)

    const int gGemm128 = (NN + 63) / 64;                 // 782
    const int gGemm32  = (NN + 127) / 128;               // 391
    const int gAggr128 = (NN * 16 + 255) / 256;          // 3125
    const int gAggr32  = (NN * 4 + 255) / 256;           // 782
    const int gNode    = (NN + 255) / 256;               // 196

    // ---- build CSR (dst-sorted) + degree-sorted node order ----
    hipMemsetAsync(bhist, 0, NBUCK * sizeof(int), stream);
    hipMemsetAsync(dhist, 0, DMAX * sizeof(int), stream);
    bucket_hist<<<NB_B, 256, 0, stream>>>(ei, bhist);
    scan_buckets<<<1, NBUCK, 0, stream>>>(bhist, bbase, bcursor, rowptr);
    bucket_bin<<<NB_B, 256, 0, stream>>>(ei, bcursor, pairs);
    bucket_sort<<<NBUCK, 256, 0, stream>>>(bbase, pairs, rowptr, sorted, dhist);
    dscan<<<1, DMAX, 0, stream>>>(dhist, dcursor);
    dperm<<<gNode, 256, 0, stream>>>(rowptr, dcursor, perm);

    // ---- layer 1 (128 -> 4x32 concat, ELU) ----
    gemm_tiled<128, 4, 8><<<gGemm128, 256, 0, stream>>>(x, W1, as1, ad1, H, ASRC, ADST);
    aggr_csr<128, 4, true><<<gAggr128, 256, 0, stream>>>(rowptr, sorted, perm, H, ASRC, ADST, b1, O);

    // ---- layer 2 (128 -> 4x32 concat, ELU) ----
    gemm_tiled<128, 4, 8><<<gGemm128, 256, 0, stream>>>(O, W2, as2, ad2, H, ASRC, ADST);
    aggr_csr<128, 4, true><<<gAggr128, 256, 0, stream>>>(rowptr, sorted, perm, H, ASRC, ADST, b2, O);

    // ---- layer 3 (128 -> 32, 1 head, no concat) ----
    gemm_tiled<32, 1, 4><<<gGemm32, 256, 0, stream>>>(O, W3, as3, ad3, H, ASRC, ADST);
    aggr_csr<32, 1, false><<<gAggr32, 256, 0, stream>>>(rowptr, sorted, perm, H, ASRC, ADST, b3, out);
}

// Round 9
// 326.005 us; speedup vs baseline: 1.8438x; 1.8438x over previous
//
#include <hip/hip_runtime.h>
#include <cmath>

constexpr int NN  = 50000;          // nodes
constexpr int EE  = 800000;         // raw edges
constexpr int E2C = EE + NN;        // edges incl. self loops = 850000
constexpr int DIM = 128;            // input dim to every layer's GEMM

// bucketed counting sort params
constexpr int NBUCK = 256;          // dst buckets
constexpr int BW    = 196;          // bucket width: 196*256 = 50176 >= NN
constexpr int EPT   = 16;           // edges per thread (hist / bin)
constexpr int CH    = 256 * EPT;    // 4096 edges per block
constexpr int NB_B  = (E2C + CH - 1) / CH;  // 208 blocks

// bf16 helpers: h is stored bf16 (gather payload); all math in fp32.
__device__ inline unsigned bf16rne(float f) {
    unsigned u = __builtin_bit_cast(unsigned, f);
    return (u + 0x7fffu + ((u >> 16) & 1u)) >> 16;     // round-nearest-even
}
__device__ inline float bflo(unsigned u) { return __builtin_bit_cast(float, u << 16); }
__device__ inline float bfhi(unsigned u) { return __builtin_bit_cast(float, u & 0xffff0000u); }

// ---------------------------------------------------------------------------
// LDS-tiled GEMM  in[N,128] @ W[128,COLS]  + fused attention coefficients.
// 256 threads; 4 x CPT register tile per thread. h output stored as bf16.
// ---------------------------------------------------------------------------
template<int COLS, int NH, int CPT>
__global__ __launch_bounds__(256) void gemm_tiled(
    const float* __restrict__ in, const float* __restrict__ W,
    const float* __restrict__ a_s, const float* __restrict__ a_d,
    unsigned short* __restrict__ hout, float* __restrict__ asrc, float* __restrict__ adst)
{
    constexpr int CG = COLS / CPT;      // col groups (16 or 8)
    constexpr int NG = 256 / CG;        // node groups (16 or 32)
    constexpr int TILE_N = NG * 4;      // 64 or 128 nodes per block
    constexpr int KT = 32;              // k tile
    constexpr int XSTR = TILE_N + 4;    // padded stride, 16B-aligned
    constexpr int NTILES = DIM / KT;    // 4
    constexpr int RL = 32 / CPT;        // lanes per head-row (4 or 8)

    __shared__ float xs[KT * XSTR];
    __shared__ float Ws[KT * COLS];

    const int tid = threadIdx.x;
    const int cc  = (tid % CG) * CPT;   // cols cc..cc+CPT-1
    const int n4  = (tid / CG) * 4;     // nodes n0+n4..n0+n4+3
    const int n0  = blockIdx.x * TILE_N;

    float acc[4][CPT] = {};

    for (int kt = 0; kt < NTILES; ++kt) {
        const int k0 = kt * KT;
        // ---- stage x (transposed) ----
        #pragma unroll
        for (int r = 0; r < TILE_N * KT / 1024; ++r) {
            int fl = tid + 256 * r;
            int nn = fl / (KT / 4);
            int kq = fl % (KT / 4);
            int row = n0 + nn; if (row >= NN) row = NN - 1;
            float4 v = *(const float4*)&in[(long long)row * DIM + k0 + kq * 4];
            xs[(kq * 4 + 0) * XSTR + nn] = v.x;
            xs[(kq * 4 + 1) * XSTR + nn] = v.y;
            xs[(kq * 4 + 2) * XSTR + nn] = v.z;
            xs[(kq * 4 + 3) * XSTR + nn] = v.w;
        }
        // ---- stage W ----
        #pragma unroll
        for (int r = 0; r < KT * COLS / 1024; ++r) {
            int fl = tid + 256 * r;
            int kk = fl / (COLS / 4);
            int cq = fl % (COLS / 4);
            *(float4*)&Ws[kk * COLS + cq * 4] =
                *(const float4*)&W[(long long)(k0 + kk) * COLS + cq * 4];
        }
        __syncthreads();
        // ---- compute ----
        #pragma unroll 8
        for (int k = 0; k < KT; ++k) {
            float4 xv4 = *(const float4*)&xs[k * XSTR + n4];
            float xv[4] = {xv4.x, xv4.y, xv4.z, xv4.w};
            float wv[CPT];
            #pragma unroll
            for (int q = 0; q < CPT / 4; ++q) {
                float4 w4 = *(const float4*)&Ws[k * COLS + cc + 4 * q];
                wv[4 * q + 0] = w4.x; wv[4 * q + 1] = w4.y;
                wv[4 * q + 2] = w4.z; wv[4 * q + 3] = w4.w;
            }
            #pragma unroll
            for (int i = 0; i < 4; ++i)
                #pragma unroll
                for (int j = 0; j < CPT; ++j)
                    acc[i][j] = fmaf(xv[i], wv[j], acc[i][j]);
        }
        __syncthreads();
    }

    // ---- epilogue: bf16 store + fused alpha reduction ----
    float asv[CPT], adv[CPT];
    #pragma unroll
    for (int j = 0; j < CPT; ++j) { asv[j] = a_s[cc + j]; adv[j] = a_d[cc + j]; }
    const int head = cc / 32;

    #pragma unroll
    for (int i = 0; i < 4; ++i) {
        const int node = n0 + n4 + i;
        const bool ok = node < NN;
        unsigned up[CPT / 2];
        #pragma unroll
        for (int j = 0; j < CPT / 2; ++j)
            up[j] = bf16rne(acc[i][2 * j]) | (bf16rne(acc[i][2 * j + 1]) << 16);
        if (ok) {
            if constexpr (CPT == 8) {
                uint4 t4; t4.x = up[0]; t4.y = up[1]; t4.z = up[2]; t4.w = up[3];
                *(uint4*)&hout[(long long)node * COLS + cc] = t4;
            } else {
                uint2 t2; t2.x = up[0]; t2.y = up[1];
                *(uint2*)&hout[(long long)node * COLS + cc] = t2;
            }
        }
        float ps = 0.f, pd = 0.f;
        #pragma unroll
        for (int j = 0; j < CPT; ++j) {
            ps = fmaf(acc[i][j], asv[j], ps);
            pd = fmaf(acc[i][j], adv[j], pd);
        }
        #pragma unroll
        for (int off = RL / 2; off > 0; off >>= 1) {
            ps += __shfl_down(ps, off, RL);
            pd += __shfl_down(pd, off, RL);
        }
        if (ok && (tid & (RL - 1)) == 0) {
            asrc[node * NH + head] = ps;
            adst[node * NH + head] = pd;
        }
    }
}

// ---------------------------------------------------------------------------
// CSR build: bucket hist -> 1-block scan -> bucket_bin -> bucket_sort
// (bucket_sort also emits a bucket-local degree-ordered node permutation,
//  all in LDS -- zero global atomic contention).
// ---------------------------------------------------------------------------
__global__ __launch_bounds__(256) void bucket_hist(
    const int* __restrict__ ei, int* __restrict__ bhist)
{
    __shared__ int cnt[NBUCK];
    const int tid = threadIdx.x;
    const long long e0 = (long long)blockIdx.x * CH;
    cnt[tid] = 0;
    __syncthreads();
    #pragma unroll
    for (int j = 0; j < EPT; ++j) {
        long long e = e0 + tid + j * 256;
        if (e < E2C) {
            int dd = (e < EE) ? ei[EE + e] : (int)(e - EE);
            atomicAdd(&cnt[dd / BW], 1);
        }
    }
    __syncthreads();
    if (cnt[tid]) atomicAdd(&bhist[tid], cnt[tid]);
}

__global__ void scan_buckets(const int* __restrict__ bhist,
                             int* __restrict__ bbase, int* __restrict__ bcursor,
                             int* __restrict__ rowptr)
{
    __shared__ int tmp[NBUCK];
    const int tid = threadIdx.x;         // <<<1, 256>>>
    int v = bhist[tid];
    tmp[tid] = v;
    __syncthreads();
    for (int off = 1; off < NBUCK; off <<= 1) {
        int t = (tid >= off) ? tmp[tid - off] : 0;
        __syncthreads();
        tmp[tid] += t;
        __syncthreads();
    }
    int excl = tmp[tid] - v;
    bbase[tid]   = excl;
    bcursor[tid] = excl;
    if (tid == NBUCK - 1) bbase[NBUCK] = tmp[tid];   // == E2C
    if (tid == 0) rowptr[NN] = E2C;
}

// bin edges into bucket-grouped pairs with LDS staging (dense global writes)
__global__ __launch_bounds__(256) void bucket_bin(
    const int* __restrict__ ei, int* __restrict__ bcursor, uint2* __restrict__ pairs)
{
    __shared__ int cnt[NBUCK];
    __shared__ int scanex[NBUCK];
    __shared__ int base[NBUCK];
    __shared__ int cur[NBUCK];
    __shared__ uint2 stage[CH];

    const int tid = threadIdx.x;
    const long long e0 = (long long)blockIdx.x * CH;
    cnt[tid] = 0;
    __syncthreads();

    int s[EPT], d[EPT], bk[EPT];
    #pragma unroll
    for (int j = 0; j < EPT; ++j) {
        long long e = e0 + tid + j * 256;
        bool valid = e < E2C;
        int ss = 0, dd = 0;
        if (valid) {
            if (e < EE) { ss = ei[e]; dd = ei[EE + e]; }
            else        { ss = dd = (int)(e - EE); }
        }
        s[j] = ss; d[j] = dd;
        bk[j] = valid ? dd / BW : -1;
        if (valid) atomicAdd(&cnt[bk[j]], 1);
    }
    __syncthreads();

    const int myc = cnt[tid];
    scanex[tid] = myc;
    __syncthreads();
    for (int off = 1; off < NBUCK; off <<= 1) {
        int t = (tid >= off) ? scanex[tid - off] : 0;
        __syncthreads();
        scanex[tid] += t;
        __syncthreads();
    }
    int excl = scanex[tid] - myc;
    __syncthreads();
    scanex[tid] = excl;
    cur[tid]    = excl;
    base[tid]   = atomicAdd(&bcursor[tid], myc);   // reserve global chunk
    __syncthreads();

    #pragma unroll
    for (int j = 0; j < EPT; ++j) {
        if (bk[j] >= 0) {
            int p = atomicAdd(&cur[bk[j]], 1);
            stage[p] = make_uint2((unsigned)s[j], (unsigned)d[j]);
        }
    }
    __syncthreads();

    const int total = (e0 + CH <= E2C) ? CH : (int)(E2C - e0);
    for (int j = tid; j < total; j += 256) {
        uint2 p = stage[j];
        int b = (int)p.y / BW;
        pairs[base[b] + (j - scanex[b])] = p;
    }
}

// one block per bucket: local hist -> local scan -> rowptr + in-window
// scatter + bucket-local degree-ordered permutation (all LDS, no global
// atomic contention).
__global__ __launch_bounds__(256) void bucket_sort(
    const int* __restrict__ bbase, const uint2* __restrict__ pairs,
    int* __restrict__ rowptr, int* __restrict__ sorted_src,
    int* __restrict__ perm)
{
    __shared__ int deg[256];       // per-node degree (BW<=256), later scan tmp
    __shared__ int cur[256];
    const int b  = blockIdx.x;
    const int n0 = b * BW;
    const int n1 = (n0 + BW < NN) ? n0 + BW : NN;
    const int nloc = n1 - n0;
    const int tid = threadIdx.x;
    const int beg = bbase[b], end = bbase[b + 1];

    deg[tid] = 0;
    __syncthreads();
    for (int i = beg + tid; i < end; i += 256)
        atomicAdd(&deg[(int)pairs[i].y - n0], 1);
    __syncthreads();

    // Hillis-Steele inclusive scan of degrees -> rowptr
    int v = deg[tid];
    cur[tid] = v;
    __syncthreads();
    for (int off = 1; off < 256; off <<= 1) {
        int t = (tid >= off) ? cur[tid - off] : 0;
        __syncthreads();
        cur[tid] += t;
        __syncthreads();
    }
    int excl = cur[tid] - v;
    __syncthreads();
    cur[tid] = beg + excl;
    if (tid < nloc) rowptr[n0 + tid] = beg + excl;
    __syncthreads();

    for (int i = beg + tid; i < end; i += 256) {
        uint2 p = pairs[i];
        int pos = atomicAdd(&cur[(int)p.y - n0], 1);
        sorted_src[pos] = (int)p.x;
    }

    // ---- bucket-local degree-ordered permutation (LDS counting sort) ----
    __syncthreads();                         // scatter done; cur reusable
    const int mydeg = (tid < nloc) ? (deg[tid] > 255 ? 255 : deg[tid]) : 0;
    cur[tid] = 0;
    __syncthreads();
    if (tid < nloc) atomicAdd(&cur[mydeg], 1);     // LDS degree hist
    __syncthreads();
    int hv = cur[tid];
    deg[tid] = hv;                                 // reuse deg as scan array
    __syncthreads();
    for (int off = 1; off < 256; off <<= 1) {
        int t = (tid >= off) ? deg[tid - off] : 0;
        __syncthreads();
        deg[tid] += t;
        __syncthreads();
    }
    int dbase = deg[tid] - hv;                     // exclusive
    __syncthreads();
    cur[tid] = dbase;                              // per-degree cursor
    __syncthreads();
    if (tid < nloc) {
        int pos = atomicAdd(&cur[mydeg], 1);       // LDS rank
        perm[n0 + pos] = n0 + tid;
    }
}

// ---------------------------------------------------------------------------
// Degree-ordered CSR gather aggregation over bf16 h: 8 channels/lane
// (uint4 = 16B), 4-edge batching, COLS/8 lanes per node. Co-wave nodes have
// ~equal degree via the bucket-local perm -> minimal divergence waste.
// ---------------------------------------------------------------------------
template<int COLS, int NH, bool DO_ELU>
__global__ __launch_bounds__(256) void aggr_csr(
    const int* __restrict__ rowptr, const int* __restrict__ sorted_src,
    const int* __restrict__ perm,
    const unsigned short* __restrict__ hin,
    const float* __restrict__ asrc, const float* __restrict__ adst,
    const float* __restrict__ bias, float* __restrict__ out)
{
    constexpr int TPN = COLS / 8;             // lanes per node: 16 or 4
    constexpr int USTR = COLS / 2;            // uints per h row
    int t = blockIdx.x * 256 + threadIdx.x;
    int g = t / TPN;
    int lc = t % TPN;                         // owns channels 8*lc .. 8*lc+7
    if (g >= NN) return;
    const int d = perm[g];
    const int cc = lc * 8;
    const int head = cc / 32;                 // 0..NH-1
    const float ad = adst[d * NH + head];
    const int beg = rowptr[d], end = rowptr[d + 1];
    const uint* hp = (const uint*)hin;

    float num[8] = {};
    float den = 0.f;

    auto accum = [&](float w, uint4 H) {
        den += w;
        num[0] = fmaf(w, bflo(H.x), num[0]); num[1] = fmaf(w, bfhi(H.x), num[1]);
        num[2] = fmaf(w, bflo(H.y), num[2]); num[3] = fmaf(w, bfhi(H.y), num[3]);
        num[4] = fmaf(w, bflo(H.z), num[4]); num[5] = fmaf(w, bfhi(H.z), num[5]);
        num[6] = fmaf(w, bflo(H.w), num[6]); num[7] = fmaf(w, bfhi(H.w), num[7]);
    };

    int i = beg;
    for (; i + 4 <= end; i += 4) {
        int s0 = sorted_src[i];
        int s1 = sorted_src[i + 1];
        int s2 = sorted_src[i + 2];
        int s3 = sorted_src[i + 3];
        float a0 = asrc[s0 * NH + head];
        float a1 = asrc[s1 * NH + head];
        float a2 = asrc[s2 * NH + head];
        float a3 = asrc[s3 * NH + head];
        uint4 H0 = *(const uint4*)&hp[(long long)s0 * USTR + cc / 2];
        uint4 H1 = *(const uint4*)&hp[(long long)s1 * USTR + cc / 2];
        uint4 H2 = *(const uint4*)&hp[(long long)s2 * USTR + cc / 2];
        uint4 H3 = *(const uint4*)&hp[(long long)s3 * USTR + cc / 2];
        float l0 = a0 + ad; l0 = l0 > 0.f ? l0 : 0.2f * l0;
        float l1 = a1 + ad; l1 = l1 > 0.f ? l1 : 0.2f * l1;
        float l2 = a2 + ad; l2 = l2 > 0.f ? l2 : 0.2f * l2;
        float l3 = a3 + ad; l3 = l3 > 0.f ? l3 : 0.2f * l3;
        accum(__builtin_expf(l0), H0);
        accum(__builtin_expf(l1), H1);
        accum(__builtin_expf(l2), H2);
        accum(__builtin_expf(l3), H3);
    }
    for (; i < end; ++i) {
        int s = sorted_src[i];
        float a = asrc[s * NH + head];
        uint4 H = *(const uint4*)&hp[(long long)s * USTR + cc / 2];
        float l = a + ad; l = l > 0.f ? l : 0.2f * l;
        accum(__builtin_expf(l), H);
    }

    float inv = 1.f / (den + 1e-16f);
    float v[8];
    #pragma unroll
    for (int j = 0; j < 8; ++j) {
        v[j] = num[j] * inv + bias[cc + j];
        if (DO_ELU) v[j] = v[j] > 0.f ? v[j] : expm1f(v[j]);
    }
    float4 o0 = {v[0], v[1], v[2], v[3]};
    float4 o1 = {v[4], v[5], v[6], v[7]};
    *(float4*)&out[(long long)d * COLS + cc]     = o0;
    *(float4*)&out[(long long)d * COLS + cc + 4] = o1;
}

// ---------------------------------------------------------------------------
extern "C" void kernel_launch(void* const* d_in, const int* in_sizes, int n_in,
                              void* d_out, int out_size, void* d_ws, size_t ws_size,
                              hipStream_t stream)
{
    const float* x   = (const float*)d_in[0];
    const int*   ei  = (const int*)  d_in[1];
    const float* W1  = (const float*)d_in[2];
    const float* as1 = (const float*)d_in[3];
    const float* ad1 = (const float*)d_in[4];
    const float* b1  = (const float*)d_in[5];
    const float* W2  = (const float*)d_in[6];
    const float* as2 = (const float*)d_in[7];
    const float* ad2 = (const float*)d_in[8];
    const float* b2  = (const float*)d_in[9];
    const float* W3  = (const float*)d_in[10];
    const float* as3 = (const float*)d_in[11];
    const float* ad3 = (const float*)d_in[12];
    const float* b3  = (const float*)d_in[13];
    float* out = (float*)d_out;

    // workspace layout
    unsigned short* H = (unsigned short*)d_ws;            // N*128 bf16 (12.8 MB)
    float* O    = (float*)(H + (size_t)NN * 128);         // N*128 f
    float* ASRC = O + (size_t)NN * 128;                   // N*4 f
    float* ADST = ASRC + (size_t)NN * 4;                  // N*4 f
    int* rowptr = (int*)(ADST + (size_t)NN * 4);          // NN+1
    int* sorted = rowptr + (NN + 1);                      // E2C
    int* perm   = sorted + E2C;                           // NN
    int* bhist  = perm + NN;                              // NBUCK
    int* bbase  = bhist + NBUCK;                          // NBUCK+1
    int* bcursor= bbase + NBUCK + 1;                      // NBUCK
    // align pairs to 16B
    size_t off = ((size_t)(bcursor + NBUCK) - (size_t)d_ws + 15) & ~(size_t)15;
    uint2* pairs = (uint2*)((char*)d_ws + off);           // E2C uint2 (6.8 MB)

    const int gGemm128 = (NN + 63) / 64;                 // 782
    const int gGemm32  = (NN + 127) / 128;               // 391
    const int gAggr128 = (NN * 16 + 255) / 256;          // 3125
    const int gAggr32  = (NN * 4 + 255) / 256;           // 782

    // ---- build CSR (dst-sorted) + bucket-local degree order ----
    hipMemsetAsync(bhist, 0, NBUCK * sizeof(int), stream);
    bucket_hist<<<NB_B, 256, 0, stream>>>(ei, bhist);
    scan_buckets<<<1, NBUCK, 0, stream>>>(bhist, bbase, bcursor, rowptr);
    bucket_bin<<<NB_B, 256, 0, stream>>>(ei, bcursor, pairs);
    bucket_sort<<<NBUCK, 256, 0, stream>>>(bbase, pairs, rowptr, sorted, perm);

    // ---- layer 1 (128 -> 4x32 concat, ELU) ----
    gemm_tiled<128, 4, 8><<<gGemm128, 256, 0, stream>>>(x, W1, as1, ad1, H, ASRC, ADST);
    aggr_csr<128, 4, true><<<gAggr128, 256, 0, stream>>>(rowptr, sorted, perm, H, ASRC, ADST, b1, O);

    // ---- layer 2 (128 -> 4x32 concat, ELU) ----
    gemm_tiled<128, 4, 8><<<gGemm128, 256, 0, stream>>>(O, W2, as2, ad2, H, ASRC, ADST);
    aggr_csr<128, 4, true><<<gAggr128, 256, 0, stream>>>(rowptr, sorted, perm, H, ASRC, ADST, b2, O);

    // ---- layer 3 (128 -> 32, 1 head, no concat) ----
    gemm_tiled<32, 1, 4><<<gGemm32, 256, 0, stream>>>(O, W3, as3, ad3, H, ASRC, ADST);
    aggr_csr<32, 1, false><<<gAggr32, 256, 0, stream>>>(rowptr, sorted, perm, H, ASRC, ADST, b3, out);
}

// Round 10
// 318.442 us; speedup vs baseline: 1.8876x; 1.0237x over previous
//
#include <hip/hip_runtime.h>
#include <cmath>

constexpr int NN  = 50000;          // nodes
constexpr int EE  = 800000;         // raw edges
constexpr int E2C = EE + NN;        // edges incl. self loops = 850000
constexpr int DIM = 128;            // input dim to every layer's GEMM

// bucketed counting sort params
constexpr int NBUCK = 256;          // dst buckets
constexpr int BW    = 196;          // bucket width: 196*256 = 50176 >= NN
constexpr int EPT   = 16;           // edges per thread (hist / bin)
constexpr int CH    = 256 * EPT;    // 4096 edges per block
constexpr int NB_B  = (E2C + CH - 1) / CH;  // 208 blocks

using bf16x8 = __attribute__((ext_vector_type(8))) short;
using f32x4  = __attribute__((ext_vector_type(4))) float;

// bf16 helpers (storage bf16, math fp32)
__device__ inline unsigned bf16rne(float f) {
    unsigned u = __builtin_bit_cast(unsigned, f);
    return (u + 0x7fffu + ((u >> 16) & 1u)) >> 16;     // round-nearest-even
}
__device__ inline float bflo(unsigned u) { return __builtin_bit_cast(float, u << 16); }
__device__ inline float bfhi(unsigned u) { return __builtin_bit_cast(float, u & 0xffff0000u); }

// ---------------------------------------------------------------------------
// fp32 -> bf16 convert (x input), 8 elems/thread
// ---------------------------------------------------------------------------
__global__ __launch_bounds__(256) void cvt_x(const float* __restrict__ x,
                                             unsigned short* __restrict__ o)
{
    long long idx = (long long)blockIdx.x * 256 + threadIdx.x;   // group of 8
    if (idx >= (long long)NN * DIM / 8) return;
    const float4* p = (const float4*)(x + idx * 8);
    float4 v0 = p[0], v1 = p[1];
    uint4 u;
    u.x = bf16rne(v0.x) | (bf16rne(v0.y) << 16);
    u.y = bf16rne(v0.z) | (bf16rne(v0.w) << 16);
    u.z = bf16rne(v1.x) | (bf16rne(v1.y) << 16);
    u.w = bf16rne(v1.z) | (bf16rne(v1.w) << 16);
    *(uint4*)(o + idx * 8) = u;
}

// ---------------------------------------------------------------------------
// W[k,c] fp32 -> Wt[c,k] bf16, all three weights in one kernel.
// group id g covers (c, k8): W1: 128*16, W2: 128*16, W3: 32*16.
// ---------------------------------------------------------------------------
__global__ __launch_bounds__(256) void cvt_weights(
    const float* __restrict__ W1, const float* __restrict__ W2,
    const float* __restrict__ W3,
    unsigned short* __restrict__ W1t, unsigned short* __restrict__ W2t,
    unsigned short* __restrict__ W3t)
{
    int g = blockIdx.x * 256 + threadIdx.x;
    const float* W; unsigned short* Wt; int cols;
    if (g < 2048)      { W = W1; Wt = W1t; cols = 128; }
    else if (g < 4096) { W = W2; Wt = W2t; cols = 128; g -= 2048; }
    else if (g < 4608) { W = W3; Wt = W3t; cols = 32;  g -= 4096; }
    else return;
    int c  = g / 16;
    int k8 = (g % 16) * 8;
    unsigned up[4];
    #pragma unroll
    for (int j = 0; j < 4; ++j) {
        float a = W[(k8 + 2 * j) * cols + c];
        float b = W[(k8 + 2 * j + 1) * cols + c];
        up[j] = bf16rne(a) | (bf16rne(b) << 16);
    }
    uint4 u; u.x = up[0]; u.y = up[1]; u.z = up[2]; u.w = up[3];
    *(uint4*)(Wt + c * 128 + k8) = u;
}

// ---------------------------------------------------------------------------
// MFMA GEMM: h[N,COLS] (bf16) = in[N,128] (bf16) @ W (via Wt[c,k] bf16).
// 256 threads = 4 waves; each wave does 16 nodes x COLS. NT = COLS/16 tiles.
// A/B fragments loaded straight from global (no LDS):
//  A[m=lane&15][k=quad*8+j] ; B[n=lane&15][k=quad*8+j] ; D row=quad*4+r, col=lane&15.
// ---------------------------------------------------------------------------
template<int NT>
__global__ __launch_bounds__(256) void gemm_mfma(
    const unsigned short* __restrict__ in16, const unsigned short* __restrict__ Wt,
    unsigned short* __restrict__ hout)
{
    constexpr int COLS = NT * 16;
    const int lane = threadIdx.x & 63;
    const int wave = threadIdx.x >> 6;
    const int m    = lane & 15;
    const int quad = lane >> 4;
    const int n0   = blockIdx.x * 64 + wave * 16;

    int arow = n0 + m; if (arow >= NN) arow = NN - 1;
    const unsigned short* ap = in16 + (long long)arow * 128 + quad * 8;

    f32x4 acc[NT] = {};
    #pragma unroll
    for (int kq = 0; kq < 4; ++kq) {
        bf16x8 a = *(const bf16x8*)(ap + kq * 32);
        #pragma unroll
        for (int t = 0; t < NT; ++t) {
            bf16x8 b = *(const bf16x8*)(Wt + (t * 16 + m) * 128 + kq * 32 + quad * 8);
            acc[t] = __builtin_amdgcn_mfma_f32_16x16x32_bf16(a, b, acc[t], 0, 0, 0);
        }
    }

    #pragma unroll
    for (int r = 0; r < 4; ++r) {
        int node = n0 + quad * 4 + r;
        if (node < NN) {
            #pragma unroll
            for (int t = 0; t < NT; ++t)
                hout[(long long)node * COLS + t * 16 + m] =
                    (unsigned short)bf16rne(acc[t][r]);
        }
    }
}

// ---------------------------------------------------------------------------
// Per-node attention coefficients from bf16 h: one thread per (node, head).
// ---------------------------------------------------------------------------
template<int NH, int COLS>
__global__ __launch_bounds__(256) void alpha_kernel(
    const unsigned short* __restrict__ h16,
    const float* __restrict__ a_s, const float* __restrict__ a_d,
    float* __restrict__ asrc, float* __restrict__ adst)
{
    int idx = blockIdx.x * 256 + threadIdx.x;
    int node = idx / NH;
    int head = idx % NH;
    if (node >= NN) return;
    const uint4* row = (const uint4*)(h16 + (long long)node * COLS + head * 32);
    float ps = 0.f, pd = 0.f;
    #pragma unroll
    for (int q = 0; q < 4; ++q) {
        uint4 u = row[q];
        unsigned w[4] = {u.x, u.y, u.z, u.w};
        #pragma unroll
        for (int j = 0; j < 4; ++j) {
            float lo = bflo(w[j]), hi = bfhi(w[j]);
            int c = head * 32 + q * 8 + 2 * j;
            ps = fmaf(lo, a_s[c], ps);     ps = fmaf(hi, a_s[c + 1], ps);
            pd = fmaf(lo, a_d[c], pd);     pd = fmaf(hi, a_d[c + 1], pd);
        }
    }
    asrc[node * NH + head] = ps;
    adst[node * NH + head] = pd;
}

// ---------------------------------------------------------------------------
// CSR build: bucket hist -> 1-block scan -> bucket_bin -> bucket_sort.
// ---------------------------------------------------------------------------
__global__ __launch_bounds__(256) void bucket_hist(
    const int* __restrict__ ei, int* __restrict__ bhist)
{
    __shared__ int cnt[NBUCK];
    const int tid = threadIdx.x;
    const long long e0 = (long long)blockIdx.x * CH;
    cnt[tid] = 0;
    __syncthreads();
    #pragma unroll
    for (int j = 0; j < EPT; ++j) {
        long long e = e0 + tid + j * 256;
        if (e < E2C) {
            int dd = (e < EE) ? ei[EE + e] : (int)(e - EE);
            atomicAdd(&cnt[dd / BW], 1);
        }
    }
    __syncthreads();
    if (cnt[tid]) atomicAdd(&bhist[tid], cnt[tid]);
}

__global__ void scan_buckets(const int* __restrict__ bhist,
                             int* __restrict__ bbase, int* __restrict__ bcursor,
                             int* __restrict__ rowptr)
{
    __shared__ int tmp[NBUCK];
    const int tid = threadIdx.x;         // <<<1, 256>>>
    int v = bhist[tid];
    tmp[tid] = v;
    __syncthreads();
    for (int off = 1; off < NBUCK; off <<= 1) {
        int t = (tid >= off) ? tmp[tid - off] : 0;
        __syncthreads();
        tmp[tid] += t;
        __syncthreads();
    }
    int excl = tmp[tid] - v;
    bbase[tid]   = excl;
    bcursor[tid] = excl;
    if (tid == NBUCK - 1) bbase[NBUCK] = tmp[tid];   // == E2C
    if (tid == 0) rowptr[NN] = E2C;
}

__global__ __launch_bounds__(256) void bucket_bin(
    const int* __restrict__ ei, int* __restrict__ bcursor, uint2* __restrict__ pairs)
{
    __shared__ int cnt[NBUCK];
    __shared__ int scanex[NBUCK];
    __shared__ int base[NBUCK];
    __shared__ int cur[NBUCK];
    __shared__ uint2 stage[CH];

    const int tid = threadIdx.x;
    const long long e0 = (long long)blockIdx.x * CH;
    cnt[tid] = 0;
    __syncthreads();

    int s[EPT], d[EPT], bk[EPT];
    #pragma unroll
    for (int j = 0; j < EPT; ++j) {
        long long e = e0 + tid + j * 256;
        bool valid = e < E2C;
        int ss = 0, dd = 0;
        if (valid) {
            if (e < EE) { ss = ei[e]; dd = ei[EE + e]; }
            else        { ss = dd = (int)(e - EE); }
        }
        s[j] = ss; d[j] = dd;
        bk[j] = valid ? dd / BW : -1;
        if (valid) atomicAdd(&cnt[bk[j]], 1);
    }
    __syncthreads();

    const int myc = cnt[tid];
    scanex[tid] = myc;
    __syncthreads();
    for (int off = 1; off < NBUCK; off <<= 1) {
        int t = (tid >= off) ? scanex[tid - off] : 0;
        __syncthreads();
        scanex[tid] += t;
        __syncthreads();
    }
    int excl = scanex[tid] - myc;
    __syncthreads();
    scanex[tid] = excl;
    cur[tid]    = excl;
    base[tid]   = atomicAdd(&bcursor[tid], myc);   // reserve global chunk
    __syncthreads();

    #pragma unroll
    for (int j = 0; j < EPT; ++j) {
        if (bk[j] >= 0) {
            int p = atomicAdd(&cur[bk[j]], 1);
            stage[p] = make_uint2((unsigned)s[j], (unsigned)d[j]);
        }
    }
    __syncthreads();

    const int total = (e0 + CH <= E2C) ? CH : (int)(E2C - e0);
    for (int j = tid; j < total; j += 256) {
        uint2 p = stage[j];
        int b = (int)p.y / BW;
        pairs[base[b] + (j - scanex[b])] = p;
    }
}

__global__ __launch_bounds__(256) void bucket_sort(
    const int* __restrict__ bbase, const uint2* __restrict__ pairs,
    int* __restrict__ rowptr, int* __restrict__ sorted_src)
{
    __shared__ int deg[256];
    __shared__ int cur[256];
    const int b  = blockIdx.x;
    const int n0 = b * BW;
    const int n1 = (n0 + BW < NN) ? n0 + BW : NN;
    const int nloc = n1 - n0;
    const int tid = threadIdx.x;
    const int beg = bbase[b], end = bbase[b + 1];

    deg[tid] = 0;
    __syncthreads();
    for (int i = beg + tid; i < end; i += 256)
        atomicAdd(&deg[(int)pairs[i].y - n0], 1);
    __syncthreads();

    int v = deg[tid];
    cur[tid] = v;
    __syncthreads();
    for (int off = 1; off < 256; off <<= 1) {
        int t = (tid >= off) ? cur[tid - off] : 0;
        __syncthreads();
        cur[tid] += t;
        __syncthreads();
    }
    int excl = cur[tid] - v;
    __syncthreads();
    cur[tid] = beg + excl;
    if (tid < nloc) rowptr[n0 + tid] = beg + excl;
    __syncthreads();

    for (int i = beg + tid; i < end; i += 256) {
        uint2 p = pairs[i];
        int pos = atomicAdd(&cur[(int)p.y - n0], 1);
        sorted_src[pos] = (int)p.x;
    }
}

// ---------------------------------------------------------------------------
// CSR gather aggregation over bf16 h (consecutive-d order, round-6 best):
// 8 channels/lane (uint4 = 16B), 4-edge batching, COLS/8 lanes per node.
// OUTBF: write bf16 (feeds next layer's MFMA GEMM) else fp32.
// ---------------------------------------------------------------------------
template<int COLS, int NH, bool DO_ELU, bool OUTBF>
__global__ __launch_bounds__(256) void aggr_csr(
    const int* __restrict__ rowptr, const int* __restrict__ sorted_src,
    const unsigned short* __restrict__ hin,
    const float* __restrict__ asrc, const float* __restrict__ adst,
    const float* __restrict__ bias, void* __restrict__ outv)
{
    constexpr int TPN = COLS / 8;             // lanes per node: 16 or 4
    constexpr int USTR = COLS / 2;            // uints per h row
    int t = blockIdx.x * 256 + threadIdx.x;
    int d = t / TPN;
    int lc = t % TPN;                         // owns channels 8*lc .. 8*lc+7
    if (d >= NN) return;
    const int cc = lc * 8;
    const int head = cc / 32;                 // 0..NH-1
    const float ad = adst[d * NH + head];
    const int beg = rowptr[d], end = rowptr[d + 1];
    const uint* hp = (const uint*)hin;

    float num[8] = {};
    float den = 0.f;

    auto accum = [&](float w, uint4 H) {
        den += w;
        num[0] = fmaf(w, bflo(H.x), num[0]); num[1] = fmaf(w, bfhi(H.x), num[1]);
        num[2] = fmaf(w, bflo(H.y), num[2]); num[3] = fmaf(w, bfhi(H.y), num[3]);
        num[4] = fmaf(w, bflo(H.z), num[4]); num[5] = fmaf(w, bfhi(H.z), num[5]);
        num[6] = fmaf(w, bflo(H.w), num[6]); num[7] = fmaf(w, bfhi(H.w), num[7]);
    };

    int i = beg;
    for (; i + 4 <= end; i += 4) {
        int s0 = sorted_src[i];
        int s1 = sorted_src[i + 1];
        int s2 = sorted_src[i + 2];
        int s3 = sorted_src[i + 3];
        float a0 = asrc[s0 * NH + head];
        float a1 = asrc[s1 * NH + head];
        float a2 = asrc[s2 * NH + head];
        float a3 = asrc[s3 * NH + head];
        uint4 H0 = *(const uint4*)&hp[(long long)s0 * USTR + cc / 2];
        uint4 H1 = *(const uint4*)&hp[(long long)s1 * USTR + cc / 2];
        uint4 H2 = *(const uint4*)&hp[(long long)s2 * USTR + cc / 2];
        uint4 H3 = *(const uint4*)&hp[(long long)s3 * USTR + cc / 2];
        float l0 = a0 + ad; l0 = l0 > 0.f ? l0 : 0.2f * l0;
        float l1 = a1 + ad; l1 = l1 > 0.f ? l1 : 0.2f * l1;
        float l2 = a2 + ad; l2 = l2 > 0.f ? l2 : 0.2f * l2;
        float l3 = a3 + ad; l3 = l3 > 0.f ? l3 : 0.2f * l3;
        accum(__builtin_expf(l0), H0);
        accum(__builtin_expf(l1), H1);
        accum(__builtin_expf(l2), H2);
        accum(__builtin_expf(l3), H3);
    }
    for (; i < end; ++i) {
        int s = sorted_src[i];
        float a = asrc[s * NH + head];
        uint4 H = *(const uint4*)&hp[(long long)s * USTR + cc / 2];
        float l = a + ad; l = l > 0.f ? l : 0.2f * l;
        accum(__builtin_expf(l), H);
    }

    float inv = 1.f / (den + 1e-16f);
    float v[8];
    #pragma unroll
    for (int j = 0; j < 8; ++j) {
        v[j] = num[j] * inv + bias[cc + j];
        if (DO_ELU) v[j] = v[j] > 0.f ? v[j] : expm1f(v[j]);
    }
    if constexpr (OUTBF) {
        uint4 u;
        u.x = bf16rne(v[0]) | (bf16rne(v[1]) << 16);
        u.y = bf16rne(v[2]) | (bf16rne(v[3]) << 16);
        u.z = bf16rne(v[4]) | (bf16rne(v[5]) << 16);
        u.w = bf16rne(v[6]) | (bf16rne(v[7]) << 16);
        *(uint4*)((unsigned short*)outv + (long long)d * COLS + cc) = u;
    } else {
        float4 o0 = {v[0], v[1], v[2], v[3]};
        float4 o1 = {v[4], v[5], v[6], v[7]};
        float* out = (float*)outv;
        *(float4*)&out[(long long)d * COLS + cc]     = o0;
        *(float4*)&out[(long long)d * COLS + cc + 4] = o1;
    }
}

// ---------------------------------------------------------------------------
extern "C" void kernel_launch(void* const* d_in, const int* in_sizes, int n_in,
                              void* d_out, int out_size, void* d_ws, size_t ws_size,
                              hipStream_t stream)
{
    const float* x   = (const float*)d_in[0];
    const int*   ei  = (const int*)  d_in[1];
    const float* W1  = (const float*)d_in[2];
    const float* as1 = (const float*)d_in[3];
    const float* ad1 = (const float*)d_in[4];
    const float* b1  = (const float*)d_in[5];
    const float* W2  = (const float*)d_in[6];
    const float* as2 = (const float*)d_in[7];
    const float* ad2 = (const float*)d_in[8];
    const float* b2  = (const float*)d_in[9];
    const float* W3  = (const float*)d_in[10];
    const float* as3 = (const float*)d_in[11];
    const float* ad3 = (const float*)d_in[12];
    const float* b3  = (const float*)d_in[13];
    float* out = (float*)d_out;

    // workspace layout (bf16 buffers first, 16B aligned)
    unsigned short* X16 = (unsigned short*)d_ws;          // N*128 bf16 (layer1 in; reused as layer2 aggr out)
    unsigned short* H16 = X16 + (size_t)NN * 128;         // N*128 bf16 (h)
    unsigned short* O16 = H16 + (size_t)NN * 128;         // N*128 bf16 (layer1 aggr out / layer2 in)
    unsigned short* W1t = O16 + (size_t)NN * 128;         // 128*128 bf16
    unsigned short* W2t = W1t + 128 * 128;                // 128*128
    unsigned short* W3t = W2t + 128 * 128;                // 32*128
    float* ASRC = (float*)(W3t + 32 * 128);               // N*4
    float* ADST = ASRC + (size_t)NN * 4;                  // N*4
    int* rowptr = (int*)(ADST + (size_t)NN * 4);          // NN+1
    int* sorted = rowptr + (NN + 1);                      // E2C
    int* bhist  = sorted + E2C;                           // NBUCK
    int* bbase  = bhist + NBUCK;                          // NBUCK+1
    int* bcursor= bbase + NBUCK + 1;                      // NBUCK
    size_t off = ((size_t)(bcursor + NBUCK) - (size_t)d_ws + 15) & ~(size_t)15;
    uint2* pairs = (uint2*)((char*)d_ws + off);           // E2C uint2 (6.8 MB)

    const int gCvtX    = (NN * DIM / 8 + 255) / 256;     // 3125
    const int gCvtW    = (4608 + 255) / 256;             // 18
    const int gGemm    = (NN + 63) / 64;                 // 782
    const int gAlpha4  = (NN * 4 + 255) / 256;           // 782
    const int gAlpha1  = (NN + 255) / 256;               // 196
    const int gAggr128 = (NN * 16 + 255) / 256;          // 3125
    const int gAggr32  = (NN * 4 + 255) / 256;           // 782

    // ---- CSR build (reused by all layers) + input/weight conversion ----
    hipMemsetAsync(bhist, 0, NBUCK * sizeof(int), stream);
    bucket_hist<<<NB_B, 256, 0, stream>>>(ei, bhist);
    scan_buckets<<<1, NBUCK, 0, stream>>>(bhist, bbase, bcursor, rowptr);
    bucket_bin<<<NB_B, 256, 0, stream>>>(ei, bcursor, pairs);
    bucket_sort<<<NBUCK, 256, 0, stream>>>(bbase, pairs, rowptr, sorted);
    cvt_x<<<gCvtX, 256, 0, stream>>>(x, X16);
    cvt_weights<<<gCvtW, 256, 0, stream>>>(W1, W2, W3, W1t, W2t, W3t);

    // ---- layer 1 (128 -> 4x32 concat, ELU) ----
    gemm_mfma<8><<<gGemm, 256, 0, stream>>>(X16, W1t, H16);
    alpha_kernel<4, 128><<<gAlpha4, 256, 0, stream>>>(H16, as1, ad1, ASRC, ADST);
    aggr_csr<128, 4, true, true><<<gAggr128, 256, 0, stream>>>(
        rowptr, sorted, H16, ASRC, ADST, b1, O16);

    // ---- layer 2 (128 -> 4x32 concat, ELU) ----
    gemm_mfma<8><<<gGemm, 256, 0, stream>>>(O16, W2t, H16);
    alpha_kernel<4, 128><<<gAlpha4, 256, 0, stream>>>(H16, as2, ad2, ASRC, ADST);
    aggr_csr<128, 4, true, true><<<gAggr128, 256, 0, stream>>>(
        rowptr, sorted, H16, ASRC, ADST, b2, X16);       // X16 reused as O2

    // ---- layer 3 (128 -> 32, 1 head, no concat) ----
    gemm_mfma<2><<<gGemm, 256, 0, stream>>>(X16, W3t, H16);   // H16 holds N*32
    alpha_kernel<1, 32><<<gAlpha1, 256, 0, stream>>>(H16, as3, ad3, ASRC, ADST);
    aggr_csr<32, 1, false, false><<<gAggr32, 256, 0, stream>>>(
        rowptr, sorted, H16, ASRC, ADST, b3, out);
}